// Round 1
// baseline (231.286 us; speedup 1.0000x reference)
//
#include <hip/hip_runtime.h>
#include <math.h>

// Blinn-Phong shading, N=4194304 elements of (light,normal,view) 3-vectors.
// Memory-bound streaming kernel: 36 B in + 12 B out per element -> 201 MB total,
// ~33 us floor at ~6 TB/s mixed-stream.
// AoS layout -> stage via LDS with coalesced float4 loads/stores.
// R2: (a) 512 elems/block (4.5 float4 loads/thread, half the barriers, deeper VMEM
//     queue); (b) wave-uniform p==16 fast path: 4 squarings instead of OCML powf
//     (~50 branchy VALU ops). powf kept as fallback for general p.

#define BLOCK 256
#define EPB   512            // elements per block
#define EPS   1e-12f

__global__ __launch_bounds__(BLOCK) void blinn_phong_kernel(
    const float* __restrict__ in,   // (n, 3, 3)
    const float* __restrict__ kd,   // (3,)
    const float* __restrict__ ks,   // (3,)
    const float* __restrict__ pp,   // (1,)
    float* __restrict__ out,        // (n, 3)
    int n)
{
    __shared__ float s_in[EPB * 9];    // 18 KB
    __shared__ float s_out[EPB * 3];   //  6 KB  -> 24 KB/block, 6 blocks/CU

    const int bid = blockIdx.x;
    const int tid = threadIdx.x;

    // ---- coalesced global->LDS stage: 1152 float4 per block ----
    const long long blk_elem0 = (long long)bid * EPB;
    const float4* gin = (const float4*)(in + blk_elem0 * 9);
    float4* s4 = (float4*)s_in;
    const long long total4 = ((long long)n * 9) >> 2;   // n*9 divisible by 4 here
    const long long base4 = blk_elem0 * 9 / 4;          // 1152 * bid

    #pragma unroll
    for (int k = 0; k < 4; ++k) {
        if (base4 + tid + k * 256 < total4) s4[tid + k * 256] = gin[tid + k * 256];
    }
    if (tid < 128 && base4 + tid + 1024 < total4) s4[tid + 1024] = gin[tid + 1024];
    __syncthreads();

    // ---- per-element math from LDS (stride-9 reads: bank permutation, free) ----
    const float kd0 = kd[0], kd1 = kd[1], kd2 = kd[2];
    const float ks0 = ks[0], ks1 = ks[1], ks2 = ks[2];
    const float p  = pp[0];
    const bool p16 = (p == 16.0f);   // wave-uniform branch

    #pragma unroll
    for (int e = 0; e < 2; ++e) {
        const int li = tid + e * 256;
        const long long elem = blk_elem0 + li;
        if (elem < n) {
            const float* v = s_in + li * 9;
            float Lx = v[0], Ly = v[1], Lz = v[2];
            float Nx = v[3], Ny = v[4], Nz = v[5];
            float Vx = v[6], Vy = v[7], Vz = v[8];

            // diffuse term
            float ln = fmaxf(0.0f, Lx * Nx + Ly * Ny + Lz * Nz);

            // half vector
            float hx = Lx + Vx, hy = Ly + Vy, hz = Lz + Vz;
            float hh = hx * hx + hy * hy + hz * hz;
            float inv = 1.0f / fmaxf(sqrtf(hh), EPS);

            float nh = fmaxf(0.0f, (Nx * hx + Ny * hy + Nz * hz) * inv);

            float spec;
            if (p16) {
                float t = nh * nh;   // nh^2
                t = t * t;           // nh^4
                t = t * t;           // nh^8
                spec = t * t;        // nh^16  (exact repeated squaring, no powf)
            } else {
                spec = powf(nh, p);
            }

            s_out[li * 3 + 0] = ks0 * spec + kd0 * ln;
            s_out[li * 3 + 1] = ks1 * spec + kd1 * ln;
            s_out[li * 3 + 2] = ks2 * spec + kd2 * ln;
        }
    }
    __syncthreads();

    // ---- coalesced LDS->global store: 384 float4 per block ----
    float4* gout = (float4*)(out + blk_elem0 * 3);
    const float4* so4 = (const float4*)s_out;
    const long long out_total4 = ((long long)n * 3) >> 2;
    const long long out_base4 = blk_elem0 * 3 / 4;      // 384 * bid
    if (out_base4 + tid < out_total4) gout[tid] = so4[tid];
    if (tid < 128 && out_base4 + tid + 256 < out_total4) gout[tid + 256] = so4[tid + 256];
}

extern "C" void kernel_launch(void* const* d_in, const int* in_sizes, int n_in,
                              void* d_out, int out_size, void* d_ws, size_t ws_size,
                              hipStream_t stream) {
    const float* in = (const float*)d_in[0];
    const float* kd = (const float*)d_in[1];
    const float* ks = (const float*)d_in[2];
    const float* pp = (const float*)d_in[3];
    float* out = (float*)d_out;

    int n = in_sizes[0] / 9;
    int grid = (n + EPB - 1) / EPB;
    blinn_phong_kernel<<<grid, BLOCK, 0, stream>>>(in, kd, ks, pp, out, n);
}